// Round 7
// baseline (84.076 us; speedup 1.0000x reference)
//
#include <hip/hip_runtime.h>

#define SS 2048
#define NN_ 32
#define HH 512
#define EE 256
#define TWO_H 1024

// d_out offsets (floats): predictions[32,10], hidden_new[2,32,512], cell_new[2,32,512]
#define OUT_PRED 0
#define OUT_H0 320
#define OUT_H1 16704
#define OUT_C0 33088
#define OUT_C1 49472

// workspace offsets (floats)
#define WS_ACC 0            // [1024][1024] attention partials, indexed by blk = chunk*32+n
#define WS_SUMW 1048576     // [1024]
#define WS_XCAT0 1049600    // [1792][32]: rows 0..1023 ctx, 1024..1279 emb, 1280..1791 hidden[0]^T
// tail regions: PG0 reuses dead ACC space; XCAT1/PG1 live above XCAT0
#define WS_PG0 0            // [7 chunks][2048 rows][32] = 458752
#define WS_XCAT1 1107008    // [1024][32]: rows 0..511 h0^T, 512..1023 hidden[1]^T
#define WS_PG1 1139776      // [8 chunks][2048 rows][32] = 524288 -> ends 1664064

__device__ __forceinline__ float wave_reduce(float v) {
  v += __shfl_xor(v, 32);
  v += __shfl_xor(v, 16);
  v += __shfl_xor(v, 8);
  v += __shfl_xor(v, 4);
  v += __shfl_xor(v, 2);
  v += __shfl_xor(v, 1);
  return v;
}

__device__ __forceinline__ float sigmoidf_(float x) { return 1.0f / (1.0f + __expf(-x)); }

// ---------------- K1: fused energy + online softmax context accumulation ----------------
// 1024 blocks, chunk-major: chunk = blk>>5, n = blk&31. 4 waves/block, 16 s-rows/wave,
// processed as 4 register-resident batches of 4 rows (interleaved reduce chains).
__global__ __launch_bounds__(256, 4) void attn_pass(
    const float* __restrict__ enc, const float* __restrict__ hidden,
    const float* __restrict__ We, const float* __restrict__ be,
    float* __restrict__ ws) {
  const int blk = blockIdx.x;
  const int chunk = blk >> 5;
  const int n = blk & 31;
  const int t = threadIdx.x;
  const int wave = t >> 6;
  const int lane = t & 63;

  const float* hl = hidden + (size_t)(NN_ + n) * HH;
  float cp;
  {
    float4 a = *(const float4*)(hl + lane * 8);
    float4 b = *(const float4*)(hl + lane * 8 + 4);
    float4 wa = *(const float4*)(We + lane * 8);
    float4 wb = *(const float4*)(We + lane * 8 + 4);
    cp = a.x * wa.x + a.y * wa.y + a.z * wa.z + a.w * wa.w +
         b.x * wb.x + b.y * wb.y + b.z * wb.z + b.w * wb.w;
  }
  cp = wave_reduce(cp);
  const float c_n = cp + be[0];

  const float4 w0 = *(const float4*)(We + HH + 0 * 256 + lane * 4);
  const float4 w1 = *(const float4*)(We + HH + 1 * 256 + lane * 4);
  const float4 w2 = *(const float4*)(We + HH + 2 * 256 + lane * 4);
  const float4 w3 = *(const float4*)(We + HH + 3 * 256 + lane * 4);

  float4 acc0 = {0, 0, 0, 0}, acc1 = {0, 0, 0, 0}, acc2 = {0, 0, 0, 0}, acc3 = {0, 0, 0, 0};
  float sumw = 0.f;

  const int sBase = chunk * 64 + wave * 16;
  const float* base = enc + ((size_t)sBase * NN_ + n) * TWO_H + lane * 4;

#pragma unroll 1
  for (int b = 0; b < 4; ++b) {
    float4 e[4][4];
    // phase A: issue all 16 independent loads (16 KB/wave in flight)
#pragma unroll
    for (int i = 0; i < 4; ++i) {
      const float* row = base + (size_t)(b * 4 + i) * (NN_ * TWO_H);
#pragma unroll
      for (int q = 0; q < 4; ++q) e[i][q] = *(const float4*)(row + q * 256);
    }
    // per-row partial dots (4 independent chains)
    float d[4];
#pragma unroll
    for (int i = 0; i < 4; ++i) {
      float s0 = e[i][0].x * w0.x + e[i][0].y * w0.y + e[i][0].z * w0.z + e[i][0].w * w0.w;
      float s1 = e[i][1].x * w1.x + e[i][1].y * w1.y + e[i][1].z * w1.z + e[i][1].w * w1.w;
      float s2 = e[i][2].x * w2.x + e[i][2].y * w2.y + e[i][2].z * w2.z + e[i][2].w * w2.w;
      float s3 = e[i][3].x * w3.x + e[i][3].y * w3.y + e[i][3].z * w3.z + e[i][3].w * w3.w;
      d[i] = (s0 + s1) + (s2 + s3);
    }
    // phase B: 6-step butterfly on 4 interleaved chains
#pragma unroll
    for (int m = 32; m >= 1; m >>= 1) {
#pragma unroll
      for (int i = 0; i < 4; ++i) d[i] += __shfl_xor(d[i], m);
    }
    float p[4];
#pragma unroll
    for (int i = 0; i < 4; ++i) {
      float en = c_n + d[i];
      en = en > 0.f ? en : 0.f;
      p[i] = __expf(en - 4.0f);
      sumw += p[i];
    }
    // phase C: accumulate from registers
#pragma unroll
    for (int i = 0; i < 4; ++i) {
      acc0.x = fmaf(p[i], e[i][0].x, acc0.x); acc0.y = fmaf(p[i], e[i][0].y, acc0.y);
      acc0.z = fmaf(p[i], e[i][0].z, acc0.z); acc0.w = fmaf(p[i], e[i][0].w, acc0.w);
      acc1.x = fmaf(p[i], e[i][1].x, acc1.x); acc1.y = fmaf(p[i], e[i][1].y, acc1.y);
      acc1.z = fmaf(p[i], e[i][1].z, acc1.z); acc1.w = fmaf(p[i], e[i][1].w, acc1.w);
      acc2.x = fmaf(p[i], e[i][2].x, acc2.x); acc2.y = fmaf(p[i], e[i][2].y, acc2.y);
      acc2.z = fmaf(p[i], e[i][2].z, acc2.z); acc2.w = fmaf(p[i], e[i][2].w, acc2.w);
      acc3.x = fmaf(p[i], e[i][3].x, acc3.x); acc3.y = fmaf(p[i], e[i][3].y, acc3.y);
      acc3.z = fmaf(p[i], e[i][3].z, acc3.z); acc3.w = fmaf(p[i], e[i][3].w, acc3.w);
    }
  }

  __shared__ __align__(16) float lacc[4][1024];
  __shared__ float lsum[4];
  *(float4*)&lacc[wave][0 * 256 + lane * 4] = acc0;
  *(float4*)&lacc[wave][1 * 256 + lane * 4] = acc1;
  *(float4*)&lacc[wave][2 * 256 + lane * 4] = acc2;
  *(float4*)&lacc[wave][3 * 256 + lane * 4] = acc3;
  if (lane == 0) lsum[wave] = sumw;
  __syncthreads();

  const int j = t * 4;
  float4 o;
  o.x = lacc[0][j + 0] + lacc[1][j + 0] + lacc[2][j + 0] + lacc[3][j + 0];
  o.y = lacc[0][j + 1] + lacc[1][j + 1] + lacc[2][j + 1] + lacc[3][j + 1];
  o.z = lacc[0][j + 2] + lacc[1][j + 2] + lacc[2][j + 2] + lacc[3][j + 2];
  o.w = lacc[0][j + 3] + lacc[1][j + 3] + lacc[2][j + 3] + lacc[3][j + 3];
  *(float4*)&ws[WS_ACC + (size_t)blk * 1024 + j] = o;
  if (t == 0) ws[WS_SUMW + blk] = lsum[0] + lsum[1] + lsum[2] + lsum[3];
}

// ---------------- K2: reduce partials -> context; build xcat0 [k][32]; 256 blocks ----------------
// ACC/SUMW are indexed blk = chunk*32 + n (chunk-major).
__global__ __launch_bounds__(256) void reduce_ctx(
    const int* __restrict__ x, const float* __restrict__ emb,
    const float* __restrict__ hidden, float* __restrict__ ws) {
  const int b = blockIdx.x;
  const int n = b >> 3;
  const int jg = b & 7;
  const int t = threadIdx.x;
  if (t < 128) {
    const int j = jg * 128 + t;
    float sumw = 0.f;
#pragma unroll
    for (int c = 0; c < 32; ++c) sumw += ws[WS_SUMW + c * 32 + n];
    const float inv = 1.0f / sumw;
    float v = 0.f;
#pragma unroll 8
    for (int c = 0; c < 32; ++c) v += ws[WS_ACC + (size_t)(c * 32 + n) * 1024 + j];
    ws[WS_XCAT0 + j * NN_ + n] = v * inv;
  } else if (t < 224) {
    const int row = jg * 96 + (t - 128);  // 0..767: 0..255 emb, 256..767 hidden[0]
    float v;
    if (row < 256) {
      v = emb[(size_t)x[n] * EE + row];
    } else {
      v = hidden[(size_t)n * HH + (row - 256)];
    }
    ws[WS_XCAT0 + (1024 + row) * NN_ + n] = v;
  }
}

// ---------------- K3: LSTM0 gates. 448 blocks = 64 hg x 7 K-chunks (Kc=256). ----------------
__global__ __launch_bounds__(256, 2) void gates0_kernel(
    const float* __restrict__ wih0, const float* __restrict__ whh0, float* __restrict__ ws) {
  __shared__ __align__(16) float xs[256 * 32];     // 32 KB
  __shared__ __align__(16) float wt[32 * 260];     // 33.3 KB
  const int bid = blockIdx.x;
  const int chunk = bid % 7;
  const int hg = bid / 7;
  const int t = threadIdx.x;
  const int nn = t & 31;
  const int rl = t >> 5;

  {
    const float* src = ws + WS_XCAT0 + (size_t)chunk * 256 * 32;
#pragma unroll
    for (int i = t * 4; i < 8192; i += 1024)
      *(float4*)&xs[i] = *(const float4*)&src[i];
  }
  {
    const int r = t >> 3;
    const int k8 = t & 7;
    const int grow = (r >> 3) * 512 + hg * 8 + (r & 7);
    const float* src = (chunk < 5) ? (wih0 + (size_t)grow * 1280 + chunk * 256)
                                   : (whh0 + (size_t)grow * 512 + (chunk - 5) * 256);
#pragma unroll
    for (int jj = 0; jj < 8; ++jj) {
      const int kl = jj * 32 + k8 * 4;
      *(float4*)&wt[r * 260 + kl] = *(const float4*)(src + kl);
    }
  }
  __syncthreads();

  const float* w0p = &wt[(0 * 8 + rl) * 260];
  const float* w1p = &wt[(1 * 8 + rl) * 260];
  const float* w2p = &wt[(2 * 8 + rl) * 260];
  const float* w3p = &wt[(3 * 8 + rl) * 260];

  float a0 = 0.f, a1 = 0.f, a2 = 0.f, a3 = 0.f;
#pragma unroll 4
  for (int k = 0; k < 256; k += 4) {
    const float4 w0 = *(const float4*)(w0p + k);
    const float4 w1 = *(const float4*)(w1p + k);
    const float4 w2 = *(const float4*)(w2p + k);
    const float4 w3 = *(const float4*)(w3p + k);
    const float x0 = xs[(k + 0) * 32 + nn];
    const float x1 = xs[(k + 1) * 32 + nn];
    const float x2 = xs[(k + 2) * 32 + nn];
    const float x3 = xs[(k + 3) * 32 + nn];
    a0 += w0.x * x0 + w0.y * x1 + w0.z * x2 + w0.w * x3;
    a1 += w1.x * x0 + w1.y * x1 + w1.z * x2 + w1.w * x3;
    a2 += w2.x * x0 + w2.y * x1 + w2.z * x2 + w2.w * x3;
    a3 += w3.x * x0 + w3.y * x1 + w3.z * x2 + w3.w * x3;
  }

  const int h = hg * 8 + rl;
  float* dst = ws + WS_PG0 + ((size_t)chunk * 2048 + h) * 32 + nn;
  dst[0 * 512 * 32] = a0;
  dst[1 * 512 * 32] = a1;
  dst[2 * 512 * 32] = a2;
  dst[3 * 512 * 32] = a3;
}

// ---------------- K4: LSTM0 combine + elementwise; writes h0/c0 and xcat1 ----------------
__global__ __launch_bounds__(256) void lstm0_kernel(
    const float* __restrict__ cell, const float* __restrict__ hidden,
    const float* __restrict__ bih0, const float* __restrict__ bhh0,
    float* __restrict__ out, float* __restrict__ ws) {
  const int g = blockIdx.x * 256 + threadIdx.x;  // 16384
  const int nn = g & 31;
  const int h = g >> 5;
  float gi = bih0[h] + bhh0[h];
  float gf = bih0[512 + h] + bhh0[512 + h];
  float gg = bih0[1024 + h] + bhh0[1024 + h];
  float go = bih0[1536 + h] + bhh0[1536 + h];
#pragma unroll
  for (int c = 0; c < 7; ++c) {
    const float* p = ws + WS_PG0 + (size_t)c * 2048 * 32;
    gi += p[(0 * 512 + h) * 32 + nn];
    gf += p[(1 * 512 + h) * 32 + nn];
    gg += p[(2 * 512 + h) * 32 + nn];
    go += p[(3 * 512 + h) * 32 + nn];
  }
  const float cprev = cell[(size_t)nn * HH + h];
  const float c0 = sigmoidf_(gf) * cprev + sigmoidf_(gi) * tanhf(gg);
  const float h0 = sigmoidf_(go) * tanhf(c0);
  out[OUT_H0 + nn * HH + h] = h0;
  out[OUT_C0 + nn * HH + h] = c0;
  ws[WS_XCAT1 + h * 32 + nn] = h0;
  ws[WS_XCAT1 + (512 + h) * 32 + nn] = hidden[(size_t)(NN_ + nn) * HH + h];
}

// ---------------- K5: LSTM1 gates. 512 blocks = 64 hg x 8 chunks (Kc=128). ----------------
__global__ __launch_bounds__(256, 2) void gates1_kernel(
    const float* __restrict__ wih1, const float* __restrict__ whh1, float* __restrict__ ws) {
  __shared__ __align__(16) float xs[128 * 32];   // 16 KB
  __shared__ __align__(16) float wt[32 * 132];   // 16.9 KB
  const int bid = blockIdx.x;
  const int chunk = bid & 7;
  const int hg = bid >> 3;
  const int t = threadIdx.x;
  const int nn = t & 31;
  const int rl = t >> 5;
  const int kb = chunk * 128;

  {
    const float* src = ws + WS_XCAT1 + (size_t)kb * 32;
#pragma unroll
    for (int i = t * 4; i < 4096; i += 1024)
      *(float4*)&xs[i] = *(const float4*)&src[i];
  }
  {
    const int r = t >> 3;
    const int k8 = t & 7;
    const int grow = (r >> 3) * 512 + hg * 8 + (r & 7);
    const float* src = (chunk < 4) ? (wih1 + (size_t)grow * 512 + kb)
                                   : (whh1 + (size_t)grow * 512 + (kb - 512));
#pragma unroll
    for (int jj = 0; jj < 4; ++jj) {
      const int kl = jj * 32 + k8 * 4;
      *(float4*)&wt[r * 132 + kl] = *(const float4*)(src + kl);
    }
  }
  __syncthreads();

  const float* w0p = &wt[(0 * 8 + rl) * 132];
  const float* w1p = &wt[(1 * 8 + rl) * 132];
  const float* w2p = &wt[(2 * 8 + rl) * 132];
  const float* w3p = &wt[(3 * 8 + rl) * 132];

  float a0 = 0.f, a1 = 0.f, a2 = 0.f, a3 = 0.f;
#pragma unroll 4
  for (int k = 0; k < 128; k += 4) {
    const float4 w0 = *(const float4*)(w0p + k);
    const float4 w1 = *(const float4*)(w1p + k);
    const float4 w2 = *(const float4*)(w2p + k);
    const float4 w3 = *(const float4*)(w3p + k);
    const float x0 = xs[(k + 0) * 32 + nn];
    const float x1 = xs[(k + 1) * 32 + nn];
    const float x2 = xs[(k + 2) * 32 + nn];
    const float x3 = xs[(k + 3) * 32 + nn];
    a0 += w0.x * x0 + w0.y * x1 + w0.z * x2 + w0.w * x3;
    a1 += w1.x * x0 + w1.y * x1 + w1.z * x2 + w1.w * x3;
    a2 += w2.x * x0 + w2.y * x1 + w2.z * x2 + w2.w * x3;
    a3 += w3.x * x0 + w3.y * x1 + w3.z * x2 + w3.w * x3;
  }

  const int h = hg * 8 + rl;
  float* dst = ws + WS_PG1 + ((size_t)chunk * 2048 + h) * 32 + nn;
  dst[0 * 512 * 32] = a0;
  dst[1 * 512 * 32] = a1;
  dst[2 * 512 * 32] = a2;
  dst[3 * 512 * 32] = a3;
}

// ---------------- K6: LSTM1 combine + elementwise; writes h1/c1 ----------------
__global__ __launch_bounds__(256) void lstm1_kernel(
    const float* __restrict__ cell,
    const float* __restrict__ bih1, const float* __restrict__ bhh1,
    float* __restrict__ out, float* __restrict__ ws) {
  const int g = blockIdx.x * 256 + threadIdx.x;
  const int nn = g & 31;
  const int h = g >> 5;
  float gi = bih1[h] + bhh1[h];
  float gf = bih1[512 + h] + bhh1[512 + h];
  float gg = bih1[1024 + h] + bhh1[1024 + h];
  float go = bih1[1536 + h] + bhh1[1536 + h];
#pragma unroll
  for (int c = 0; c < 8; ++c) {
    const float* p = ws + WS_PG1 + (size_t)c * 2048 * 32;
    gi += p[(0 * 512 + h) * 32 + nn];
    gf += p[(1 * 512 + h) * 32 + nn];
    gg += p[(2 * 512 + h) * 32 + nn];
    go += p[(3 * 512 + h) * 32 + nn];
  }
  const float cprev = cell[(size_t)(NN_ + nn) * HH + h];
  const float c1 = sigmoidf_(gf) * cprev + sigmoidf_(gi) * tanhf(gg);
  const float h1 = sigmoidf_(go) * tanhf(c1);
  out[OUT_H1 + nn * HH + h] = h1;
  out[OUT_C1 + nn * HH + h] = c1;
}

// ---------------- K7: predictions ----------------
__global__ __launch_bounds__(256) void pred_kernel(
    const float* __restrict__ Wc, const float* __restrict__ bc, float* out) {
  const int wid = blockIdx.x * 4 + (threadIdx.x >> 6);  // 0..319
  const int lane = threadIdx.x & 63;
  const int nn = wid / 10;
  const int c = wid % 10;
  const float* hp = out + OUT_H1 + (size_t)nn * HH;
  const float* wp = Wc + (size_t)c * HH;
  float p = 0.f;
#pragma unroll
  for (int j = 0; j < 8; ++j) p += hp[lane * 8 + j] * wp[lane * 8 + j];
  p = wave_reduce(p);
  if (lane == 0) out[OUT_PRED + nn * 10 + c] = p + bc[c];
}

extern "C" void kernel_launch(void* const* d_in, const int* in_sizes, int n_in,
                              void* d_out, int out_size, void* d_ws, size_t ws_size,
                              hipStream_t stream) {
  const int* x = (const int*)d_in[0];
  const float* enc = (const float*)d_in[1];
  const float* hidden = (const float*)d_in[2];
  const float* cell = (const float*)d_in[3];
  const float* We = (const float*)d_in[4];
  const float* be = (const float*)d_in[5];
  const float* emb = (const float*)d_in[6];
  const float* wih0 = (const float*)d_in[7];
  const float* whh0 = (const float*)d_in[8];
  const float* bih0 = (const float*)d_in[9];
  const float* bhh0 = (const float*)d_in[10];
  const float* wih1 = (const float*)d_in[11];
  const float* whh1 = (const float*)d_in[12];
  const float* bih1 = (const float*)d_in[13];
  const float* bhh1 = (const float*)d_in[14];
  const float* Wc = (const float*)d_in[15];
  const float* bc = (const float*)d_in[16];
  float* out = (float*)d_out;
  float* ws = (float*)d_ws;

  hipLaunchKernelGGL(attn_pass, dim3(1024), dim3(256), 0, stream, enc, hidden, We, be, ws);
  hipLaunchKernelGGL(reduce_ctx, dim3(256), dim3(256), 0, stream, x, emb, hidden, ws);
  hipLaunchKernelGGL(gates0_kernel, dim3(448), dim3(256), 0, stream, wih0, whh0, ws);
  hipLaunchKernelGGL(lstm0_kernel, dim3(64), dim3(256), 0, stream, cell, hidden, bih0, bhh0, out, ws);
  hipLaunchKernelGGL(gates1_kernel, dim3(512), dim3(256), 0, stream, wih1, whh1, ws);
  hipLaunchKernelGGL(lstm1_kernel, dim3(64), dim3(256), 0, stream, cell, bih1, bhh1, out, ws);
  hipLaunchKernelGGL(pred_kernel, dim3(80), dim3(256), 0, stream, Wc, bc, out);
}

// Round 9
// 79.574 us; speedup vs baseline: 1.0566x; 1.0566x over previous
//
#include <hip/hip_runtime.h>

#define SS 2048
#define NN_ 32
#define HH 512
#define EE 256
#define TWO_H 1024

// d_out offsets (floats): predictions[32,10], hidden_new[2,32,512], cell_new[2,32,512]
#define OUT_PRED 0
#define OUT_H0 320
#define OUT_H1 16704
#define OUT_C0 33088
#define OUT_C1 49472

// workspace offsets (floats)
#define WS_ACC 0            // [1024][1024] attention partials (dead after reduce_ctx)
#define WS_SUMW 1048576     // [1024]
#define WS_XCAT0 1049600    // [1792][32]: rows 0..1023 ctx, 1024..1279 emb, 1280..1791 hidden[0]^T
// tail regions: PG0 reuses dead ACC space; XCAT1/PG1 live above XCAT0
#define WS_PG0 0            // [7 chunks][2048 rows][32] = 458752
#define WS_XCAT1 1107008    // [1024][32]: rows 0..511 h0^T, 512..1023 hidden[1]^T
#define WS_PG1 1139776      // [8 chunks][2048 rows][32] = 524288 -> ends 1664064

typedef float f32x4 __attribute__((ext_vector_type(4)));

__device__ __forceinline__ float wave_reduce(float v) {
  v += __shfl_xor(v, 32);
  v += __shfl_xor(v, 16);
  v += __shfl_xor(v, 8);
  v += __shfl_xor(v, 4);
  v += __shfl_xor(v, 2);
  v += __shfl_xor(v, 1);
  return v;
}

__device__ __forceinline__ float sigmoidf_(float x) { return 1.0f / (1.0f + __expf(-x)); }

// non-temporal 16B load via native clang vector type (builtin rejects HIP_vector_type)
__device__ __forceinline__ f32x4 nt_load4(const float* p) {
  return __builtin_nontemporal_load((const f32x4*)p);
}

// ---------------- K1: fused energy + online softmax-weighted context accumulation ----------------
// Identical to the 78.9us round-3 kernel EXCEPT enc loads are non-temporal (bypass L3 alloc).
__global__ __launch_bounds__(256, 4) void attn_pass(
    const float* __restrict__ enc, const float* __restrict__ hidden,
    const float* __restrict__ We, const float* __restrict__ be,
    float* __restrict__ ws) {
  const int blk = blockIdx.x;
  const int n = blk >> 5;
  const int chunk = blk & 31;
  const int t = threadIdx.x;
  const int wave = t >> 6;
  const int lane = t & 63;

  const float* hl = hidden + (size_t)(NN_ + n) * HH;
  float cp;
  {
    float4 a = *(const float4*)(hl + lane * 8);
    float4 b = *(const float4*)(hl + lane * 8 + 4);
    float4 wa = *(const float4*)(We + lane * 8);
    float4 wb = *(const float4*)(We + lane * 8 + 4);
    cp = a.x * wa.x + a.y * wa.y + a.z * wa.z + a.w * wa.w +
         b.x * wb.x + b.y * wb.y + b.z * wb.z + b.w * wb.w;
  }
  cp = wave_reduce(cp);
  const float c_n = cp + be[0];

  const float4 w0 = *(const float4*)(We + HH + 0 * 256 + lane * 4);
  const float4 w1 = *(const float4*)(We + HH + 1 * 256 + lane * 4);
  const float4 w2 = *(const float4*)(We + HH + 2 * 256 + lane * 4);
  const float4 w3 = *(const float4*)(We + HH + 3 * 256 + lane * 4);

  float4 acc0 = {0, 0, 0, 0}, acc1 = {0, 0, 0, 0}, acc2 = {0, 0, 0, 0}, acc3 = {0, 0, 0, 0};
  float sumw = 0.f;

  const int sBase = chunk * 64 + wave * 16;
#pragma unroll 2
  for (int i = 0; i < 16; ++i) {
    const float* row = enc + ((size_t)(sBase + i) * NN_ + n) * TWO_H;
    f32x4 e0 = nt_load4(row + 0 * 256 + lane * 4);
    f32x4 e1 = nt_load4(row + 1 * 256 + lane * 4);
    f32x4 e2 = nt_load4(row + 2 * 256 + lane * 4);
    f32x4 e3 = nt_load4(row + 3 * 256 + lane * 4);
    float d = e0.x * w0.x + e0.y * w0.y + e0.z * w0.z + e0.w * w0.w +
              e1.x * w1.x + e1.y * w1.y + e1.z * w1.z + e1.w * w1.w +
              e2.x * w2.x + e2.y * w2.y + e2.z * w2.z + e2.w * w2.w +
              e3.x * w3.x + e3.y * w3.y + e3.z * w3.z + e3.w * w3.w;
    d = wave_reduce(d);
    float en = c_n + d;
    en = en > 0.f ? en : 0.f;
    float p = __expf(en - 4.0f);
    sumw += p;
    acc0.x = fmaf(p, e0.x, acc0.x); acc0.y = fmaf(p, e0.y, acc0.y);
    acc0.z = fmaf(p, e0.z, acc0.z); acc0.w = fmaf(p, e0.w, acc0.w);
    acc1.x = fmaf(p, e1.x, acc1.x); acc1.y = fmaf(p, e1.y, acc1.y);
    acc1.z = fmaf(p, e1.z, acc1.z); acc1.w = fmaf(p, e1.w, acc1.w);
    acc2.x = fmaf(p, e2.x, acc2.x); acc2.y = fmaf(p, e2.y, acc2.y);
    acc2.z = fmaf(p, e2.z, acc2.z); acc2.w = fmaf(p, e2.w, acc2.w);
    acc3.x = fmaf(p, e3.x, acc3.x); acc3.y = fmaf(p, e3.y, acc3.y);
    acc3.z = fmaf(p, e3.z, acc3.z); acc3.w = fmaf(p, e3.w, acc3.w);
  }

  __shared__ __align__(16) float lacc[4][1024];
  __shared__ float lsum[4];
  *(float4*)&lacc[wave][0 * 256 + lane * 4] = acc0;
  *(float4*)&lacc[wave][1 * 256 + lane * 4] = acc1;
  *(float4*)&lacc[wave][2 * 256 + lane * 4] = acc2;
  *(float4*)&lacc[wave][3 * 256 + lane * 4] = acc3;
  if (lane == 0) lsum[wave] = sumw;
  __syncthreads();

  const int j = t * 4;
  float4 o;
  o.x = lacc[0][j + 0] + lacc[1][j + 0] + lacc[2][j + 0] + lacc[3][j + 0];
  o.y = lacc[0][j + 1] + lacc[1][j + 1] + lacc[2][j + 1] + lacc[3][j + 1];
  o.z = lacc[0][j + 2] + lacc[1][j + 2] + lacc[2][j + 2] + lacc[3][j + 2];
  o.w = lacc[0][j + 3] + lacc[1][j + 3] + lacc[2][j + 3] + lacc[3][j + 3];
  *(float4*)&ws[WS_ACC + (size_t)blk * 1024 + j] = o;
  if (t == 0) ws[WS_SUMW + blk] = lsum[0] + lsum[1] + lsum[2] + lsum[3];
}

// ---------------- K2: reduce partials -> context; build xcat0 [k][32]; 256 blocks ----------------
__global__ __launch_bounds__(256) void reduce_ctx(
    const int* __restrict__ x, const float* __restrict__ emb,
    const float* __restrict__ hidden, float* __restrict__ ws) {
  const int b = blockIdx.x;
  const int n = b >> 3;
  const int jg = b & 7;
  const int t = threadIdx.x;
  if (t < 128) {
    const int j = jg * 128 + t;
    float sumw = 0.f;
#pragma unroll
    for (int c = 0; c < 32; ++c) sumw += ws[WS_SUMW + n * 32 + c];
    const float inv = 1.0f / sumw;
    float v = 0.f;
#pragma unroll 8
    for (int c = 0; c < 32; ++c) v += ws[WS_ACC + (size_t)(n * 32 + c) * 1024 + j];
    ws[WS_XCAT0 + j * NN_ + n] = v * inv;
  } else if (t < 224) {
    const int row = jg * 96 + (t - 128);  // 0..767: 0..255 emb, 256..767 hidden[0]
    float v;
    if (row < 256) {
      v = emb[(size_t)x[n] * EE + row];
    } else {
      v = hidden[(size_t)n * HH + (row - 256)];
    }
    ws[WS_XCAT0 + (1024 + row) * NN_ + n] = v;
  }
}

// ---------------- K3: LSTM0 gates. 448 blocks = 64 hg x 7 K-chunks (Kc=256). ----------------
__global__ __launch_bounds__(256, 2) void gates0_kernel(
    const float* __restrict__ wih0, const float* __restrict__ whh0, float* __restrict__ ws) {
  __shared__ __align__(16) float xs[256 * 32];     // 32 KB
  __shared__ __align__(16) float wt[32 * 260];     // 33.3 KB
  const int bid = blockIdx.x;
  const int chunk = bid % 7;
  const int hg = bid / 7;
  const int t = threadIdx.x;
  const int nn = t & 31;
  const int rl = t >> 5;

  {
    const float* src = ws + WS_XCAT0 + (size_t)chunk * 256 * 32;
#pragma unroll
    for (int i = t * 4; i < 8192; i += 1024)
      *(float4*)&xs[i] = *(const float4*)&src[i];
  }
  {
    const int r = t >> 3;
    const int k8 = t & 7;
    const int grow = (r >> 3) * 512 + hg * 8 + (r & 7);
    const float* src = (chunk < 5) ? (wih0 + (size_t)grow * 1280 + chunk * 256)
                                   : (whh0 + (size_t)grow * 512 + (chunk - 5) * 256);
#pragma unroll
    for (int jj = 0; jj < 8; ++jj) {
      const int kl = jj * 32 + k8 * 4;
      *(float4*)&wt[r * 260 + kl] = *(const float4*)(src + kl);
    }
  }
  __syncthreads();

  const float* w0p = &wt[(0 * 8 + rl) * 260];
  const float* w1p = &wt[(1 * 8 + rl) * 260];
  const float* w2p = &wt[(2 * 8 + rl) * 260];
  const float* w3p = &wt[(3 * 8 + rl) * 260];

  float a0 = 0.f, a1 = 0.f, a2 = 0.f, a3 = 0.f;
#pragma unroll 4
  for (int k = 0; k < 256; k += 4) {
    const float4 w0 = *(const float4*)(w0p + k);
    const float4 w1 = *(const float4*)(w1p + k);
    const float4 w2 = *(const float4*)(w2p + k);
    const float4 w3 = *(const float4*)(w3p + k);
    const float x0 = xs[(k + 0) * 32 + nn];
    const float x1 = xs[(k + 1) * 32 + nn];
    const float x2 = xs[(k + 2) * 32 + nn];
    const float x3 = xs[(k + 3) * 32 + nn];
    a0 += w0.x * x0 + w0.y * x1 + w0.z * x2 + w0.w * x3;
    a1 += w1.x * x0 + w1.y * x1 + w1.z * x2 + w1.w * x3;
    a2 += w2.x * x0 + w2.y * x1 + w2.z * x2 + w2.w * x3;
    a3 += w3.x * x0 + w3.y * x1 + w3.z * x2 + w3.w * x3;
  }

  const int h = hg * 8 + rl;
  float* dst = ws + WS_PG0 + ((size_t)chunk * 2048 + h) * 32 + nn;
  dst[0 * 512 * 32] = a0;
  dst[1 * 512 * 32] = a1;
  dst[2 * 512 * 32] = a2;
  dst[3 * 512 * 32] = a3;
}

// ---------------- K4: LSTM0 combine + elementwise; writes h0/c0 and xcat1 ----------------
__global__ __launch_bounds__(256) void lstm0_kernel(
    const float* __restrict__ cell, const float* __restrict__ hidden,
    const float* __restrict__ bih0, const float* __restrict__ bhh0,
    float* __restrict__ out, float* __restrict__ ws) {
  const int g = blockIdx.x * 256 + threadIdx.x;  // 16384
  const int nn = g & 31;
  const int h = g >> 5;
  float gi = bih0[h] + bhh0[h];
  float gf = bih0[512 + h] + bhh0[512 + h];
  float gg = bih0[1024 + h] + bhh0[1024 + h];
  float go = bih0[1536 + h] + bhh0[1536 + h];
#pragma unroll
  for (int c = 0; c < 7; ++c) {
    const float* p = ws + WS_PG0 + (size_t)c * 2048 * 32;
    gi += p[(0 * 512 + h) * 32 + nn];
    gf += p[(1 * 512 + h) * 32 + nn];
    gg += p[(2 * 512 + h) * 32 + nn];
    go += p[(3 * 512 + h) * 32 + nn];
  }
  const float cprev = cell[(size_t)nn * HH + h];
  const float c0 = sigmoidf_(gf) * cprev + sigmoidf_(gi) * tanhf(gg);
  const float h0 = sigmoidf_(go) * tanhf(c0);
  out[OUT_H0 + nn * HH + h] = h0;
  out[OUT_C0 + nn * HH + h] = c0;
  ws[WS_XCAT1 + h * 32 + nn] = h0;
  ws[WS_XCAT1 + (512 + h) * 32 + nn] = hidden[(size_t)(NN_ + nn) * HH + h];
}

// ---------------- K5: LSTM1 gates. 512 blocks = 64 hg x 8 chunks (Kc=128). ----------------
__global__ __launch_bounds__(256, 2) void gates1_kernel(
    const float* __restrict__ wih1, const float* __restrict__ whh1, float* __restrict__ ws) {
  __shared__ __align__(16) float xs[128 * 32];   // 16 KB
  __shared__ __align__(16) float wt[32 * 132];   // 16.9 KB
  const int bid = blockIdx.x;
  const int chunk = bid & 7;
  const int hg = bid >> 3;
  const int t = threadIdx.x;
  const int nn = t & 31;
  const int rl = t >> 5;
  const int kb = chunk * 128;

  {
    const float* src = ws + WS_XCAT1 + (size_t)kb * 32;
#pragma unroll
    for (int i = t * 4; i < 4096; i += 1024)
      *(float4*)&xs[i] = *(const float4*)&src[i];
  }
  {
    const int r = t >> 3;
    const int k8 = t & 7;
    const int grow = (r >> 3) * 512 + hg * 8 + (r & 7);
    const float* src = (chunk < 4) ? (wih1 + (size_t)grow * 512 + kb)
                                   : (whh1 + (size_t)grow * 512 + (kb - 512));
#pragma unroll
    for (int jj = 0; jj < 4; ++jj) {
      const int kl = jj * 32 + k8 * 4;
      *(float4*)&wt[r * 132 + kl] = *(const float4*)(src + kl);
    }
  }
  __syncthreads();

  const float* w0p = &wt[(0 * 8 + rl) * 132];
  const float* w1p = &wt[(1 * 8 + rl) * 132];
  const float* w2p = &wt[(2 * 8 + rl) * 132];
  const float* w3p = &wt[(3 * 8 + rl) * 132];

  float a0 = 0.f, a1 = 0.f, a2 = 0.f, a3 = 0.f;
#pragma unroll 4
  for (int k = 0; k < 128; k += 4) {
    const float4 w0 = *(const float4*)(w0p + k);
    const float4 w1 = *(const float4*)(w1p + k);
    const float4 w2 = *(const float4*)(w2p + k);
    const float4 w3 = *(const float4*)(w3p + k);
    const float x0 = xs[(k + 0) * 32 + nn];
    const float x1 = xs[(k + 1) * 32 + nn];
    const float x2 = xs[(k + 2) * 32 + nn];
    const float x3 = xs[(k + 3) * 32 + nn];
    a0 += w0.x * x0 + w0.y * x1 + w0.z * x2 + w0.w * x3;
    a1 += w1.x * x0 + w1.y * x1 + w1.z * x2 + w1.w * x3;
    a2 += w2.x * x0 + w2.y * x1 + w2.z * x2 + w2.w * x3;
    a3 += w3.x * x0 + w3.y * x1 + w3.z * x2 + w3.w * x3;
  }

  const int h = hg * 8 + rl;
  float* dst = ws + WS_PG1 + ((size_t)chunk * 2048 + h) * 32 + nn;
  dst[0 * 512 * 32] = a0;
  dst[1 * 512 * 32] = a1;
  dst[2 * 512 * 32] = a2;
  dst[3 * 512 * 32] = a3;
}

// ---------------- K6: LSTM1 combine + elementwise; writes h1/c1 ----------------
__global__ __launch_bounds__(256) void lstm1_kernel(
    const float* __restrict__ cell,
    const float* __restrict__ bih1, const float* __restrict__ bhh1,
    float* __restrict__ out, float* __restrict__ ws) {
  const int g = blockIdx.x * 256 + threadIdx.x;
  const int nn = g & 31;
  const int h = g >> 5;
  float gi = bih1[h] + bhh1[h];
  float gf = bih1[512 + h] + bhh1[512 + h];
  float gg = bih1[1024 + h] + bhh1[1024 + h];
  float go = bih1[1536 + h] + bhh1[1536 + h];
#pragma unroll
  for (int c = 0; c < 8; ++c) {
    const float* p = ws + WS_PG1 + (size_t)c * 2048 * 32;
    gi += p[(0 * 512 + h) * 32 + nn];
    gf += p[(1 * 512 + h) * 32 + nn];
    gg += p[(2 * 512 + h) * 32 + nn];
    go += p[(3 * 512 + h) * 32 + nn];
  }
  const float cprev = cell[(size_t)(NN_ + nn) * HH + h];
  const float c1 = sigmoidf_(gf) * cprev + sigmoidf_(gi) * tanhf(gg);
  const float h1 = sigmoidf_(go) * tanhf(c1);
  out[OUT_H1 + nn * HH + h] = h1;
  out[OUT_C1 + nn * HH + h] = c1;
}

// ---------------- K7: predictions ----------------
__global__ __launch_bounds__(256) void pred_kernel(
    const float* __restrict__ Wc, const float* __restrict__ bc, float* out) {
  const int wid = blockIdx.x * 4 + (threadIdx.x >> 6);  // 0..319
  const int lane = threadIdx.x & 63;
  const int nn = wid / 10;
  const int c = wid % 10;
  const float* hp = out + OUT_H1 + (size_t)nn * HH;
  const float* wp = Wc + (size_t)c * HH;
  float p = 0.f;
#pragma unroll
  for (int j = 0; j < 8; ++j) p += hp[lane * 8 + j] * wp[lane * 8 + j];
  p = wave_reduce(p);
  if (lane == 0) out[OUT_PRED + nn * 10 + c] = p + bc[c];
}

extern "C" void kernel_launch(void* const* d_in, const int* in_sizes, int n_in,
                              void* d_out, int out_size, void* d_ws, size_t ws_size,
                              hipStream_t stream) {
  const int* x = (const int*)d_in[0];
  const float* enc = (const float*)d_in[1];
  const float* hidden = (const float*)d_in[2];
  const float* cell = (const float*)d_in[3];
  const float* We = (const float*)d_in[4];
  const float* be = (const float*)d_in[5];
  const float* emb = (const float*)d_in[6];
  const float* wih0 = (const float*)d_in[7];
  const float* whh0 = (const float*)d_in[8];
  const float* bih0 = (const float*)d_in[9];
  const float* bhh0 = (const float*)d_in[10];
  const float* wih1 = (const float*)d_in[11];
  const float* whh1 = (const float*)d_in[12];
  const float* bih1 = (const float*)d_in[13];
  const float* bhh1 = (const float*)d_in[14];
  const float* Wc = (const float*)d_in[15];
  const float* bc = (const float*)d_in[16];
  float* out = (float*)d_out;
  float* ws = (float*)d_ws;

  hipLaunchKernelGGL(attn_pass, dim3(1024), dim3(256), 0, stream, enc, hidden, We, be, ws);
  hipLaunchKernelGGL(reduce_ctx, dim3(256), dim3(256), 0, stream, x, emb, hidden, ws);
  hipLaunchKernelGGL(gates0_kernel, dim3(448), dim3(256), 0, stream, wih0, whh0, ws);
  hipLaunchKernelGGL(lstm0_kernel, dim3(64), dim3(256), 0, stream, cell, hidden, bih0, bhh0, out, ws);
  hipLaunchKernelGGL(gates1_kernel, dim3(512), dim3(256), 0, stream, wih1, whh1, ws);
  hipLaunchKernelGGL(lstm1_kernel, dim3(64), dim3(256), 0, stream, cell, bih1, bhh1, out, ws);
  hipLaunchKernelGGL(pred_kernel, dim3(80), dim3(256), 0, stream, Wc, bc, out);
}